// Round 22
// baseline (210.029 us; speedup 1.0000x reference)
//
#include <hip/hip_runtime.h>
#include <math.h>

#define DIN 128
#define DOUT 64

#define NBLK 64             // binning blocks (write locality: ~32-edge runs)
#define BK_SHIFT 7          // 128 cols per bucket
#define BK_COLS 128
#define NBK_STRIDE 1024     // LDS hist stride
#define REGION 4096         // fixed slots per bucket (max bucket ~2205)
#define CCAP 3072           // LDS staging capacity in csr_gather

__device__ __forceinline__ float safe_pow(float d, float e) {
    float p = powf(d, e);
    return isinf(p) ? 0.0f : p;
}

__device__ __forceinline__ float dot4(float4 a, float4 b) {
    return a.x * b.x + a.y * b.y + a.z * b.z + a.w * b.w;
}

__device__ __forceinline__ unsigned short f32_to_bf16(float f) {
    unsigned bits = __float_as_uint(f);
    unsigned r = (bits + 0x7FFFu + ((bits >> 16) & 1u)) >> 16;
    return (unsigned short)r;
}

// ---------------------------------------------------------------------------
// Plain multi-block 64x64 matmul (8/16 blocks). B SYMMETRIC (rows as cols).
// Optional CB = 1.5I - 0.5*C. Separate ~3µs launches (grid.sync costs ~9µs).
// ---------------------------------------------------------------------------
__global__ __launch_bounds__(256) void mm_pass(const float* A1, const float* A2,
                                               const float* Bsrc,
                                               float* C1, float* C2, float* CB) {
    int t = threadIdx.x;
    bool second = (blockIdx.x >= 8);
    int blk = blockIdx.x & 7;
    const float* As = second ? A2 : A1;
    float* Cs = second ? C2 : C1;
    int c = t & 63;
    int r0 = blk * 8 + (t >> 6) * 2;
    float acc0 = 0.f, acc1 = 0.f;
#pragma unroll
    for (int k4 = 0; k4 < 16; ++k4) {
        float4 b  = *(const float4*)&Bsrc[c * 64 + k4 * 4];
        float4 a0 = *(const float4*)&As[r0 * 64 + k4 * 4];
        float4 a1 = *(const float4*)&As[(r0 + 1) * 64 + k4 * 4];
        acc0 += dot4(a0, b);
        acc1 += dot4(a1, b);
    }
    Cs[r0 * 64 + c] = acc0;
    Cs[(r0 + 1) * 64 + c] = acc1;
    if (CB != nullptr && !second) {
        CB[r0 * 64 + c]       = ((r0 == c)     ? 1.5f : 0.0f) - 0.5f * acc0;
        CB[(r0 + 1) * 64 + c] = ((r0 + 1 == c) ? 1.5f : 0.0f) - 0.5f * acc1;
    }
}

// ---------------------------------------------------------------------------
// G = W @ W^T (64x64, K=128), 8 blocks.
// ---------------------------------------------------------------------------
__global__ __launch_bounds__(256) void gram_pass(const float* W, float* G) {
    int t = threadIdx.x;
    int c = t & 63;
    int r0 = blockIdx.x * 8 + (t >> 6) * 2;
    float acc0 = 0.f, acc1 = 0.f;
#pragma unroll
    for (int k4 = 0; k4 < 32; ++k4) {
        float4 b  = *(const float4*)&W[c * 128 + k4 * 4];
        float4 a0 = *(const float4*)&W[r0 * 128 + k4 * 4];
        float4 a1 = *(const float4*)&W[(r0 + 1) * 128 + k4 * 4];
        acc0 += dot4(a0, b);
        acc1 += dot4(a1, b);
    }
    G[r0 * 64 + c] = acc0;
    G[(r0 + 1) * 64 + c] = acc1;
}

// ---------------------------------------------------------------------------
// power iteration on H2 = G^4 (wave 0) + prep A0 = rs*G, B0 = 1.5I - 0.5*A0.
// ---------------------------------------------------------------------------
__global__ __launch_bounds__(256) void power_prep(const float* gH2, const float* gG,
                                                  float* gSc, float* gA0, float* gB0) {
    __shared__ float sS[2];
    int t = threadIdx.x;
    if (t < 64) {
        float tr = gH2[t * 65];
#pragma unroll
        for (int d = 1; d < 64; d <<= 1) tr += __shfl_xor(tr, d);
        float inv_tr = 1.0f / tr;
        float4 g4[16];
#pragma unroll
        for (int j4 = 0; j4 < 16; ++j4) {
            float4 v = *(const float4*)&gH2[t * 64 + j4 * 4];
            v.x *= inv_tr; v.y *= inv_tr; v.z *= inv_tr; v.w *= inv_tr;
            g4[j4] = v;
        }
        unsigned h = (unsigned)t * 2654435761u;
        float xv = 0.5f + (float)((h >> 17) & 0x7fff) * (1.0f / 32768.0f);
        float yv = 0.f;
        for (int it = 0; it < 8; ++it) {
            float p0 = 0.f, p1 = 0.f, p2 = 0.f, p3 = 0.f;
#pragma unroll
            for (int j4 = 0; j4 < 16; ++j4) {
                float4 xx;
                xx.x = __shfl(xv, j4 * 4 + 0);
                xx.y = __shfl(xv, j4 * 4 + 1);
                xx.z = __shfl(xv, j4 * 4 + 2);
                xx.w = __shfl(xv, j4 * 4 + 3);
                float dd = dot4(g4[j4], xx);
                if (j4 < 4) p0 += dd; else if (j4 < 8) p1 += dd;
                else if (j4 < 12) p2 += dd; else p3 += dd;
            }
            yv = (p0 + p1) + (p2 + p3);
            if (it < 7) xv = yv;
        }
        float num = xv * yv, den = xv * xv;
#pragma unroll
        for (int d = 1; d < 64; d <<= 1) {
            num += __shfl_xor(num, d);
            den += __shfl_xor(den, d);
        }
        if (t == 0) {
            float lam_h2 = tr * num / den;        // = sigma^8
            float sig = powf(lam_h2, 0.125f);
            float sc = 1.0f / (1.1f * sig);
            float rs = 1.0f / (1.21f * sig * sig);
            gSc[0] = sc; gSc[1] = rs;
            sS[0] = sc; sS[1] = rs;
        }
    }
    __syncthreads();
    float rs = sS[1];
    for (int idx = t; idx < 4096; idx += 256) {
        int r = idx >> 6, c2 = idx & 63;
        float a0 = rs * gG[idx];
        gA0[idx] = a0;
        gB0[idx] = ((r == c2) ? 1.5f : 0.0f) - 0.5f * a0;
    }
}

// ---------------------------------------------------------------------------
// Wo = sc * P @ W  (64x128), 8 blocks.
// ---------------------------------------------------------------------------
__global__ __launch_bounds__(256) void wo_pass(const float* W, const float* P,
                                               const float* gSc, float* Wo) {
    int t = threadIdx.x;
    int c = t & 63;
    int r0 = blockIdx.x * 8 + (t >> 6) * 2;
    float a00 = 0.f, a01 = 0.f, a10 = 0.f, a11 = 0.f;
#pragma unroll 4
    for (int j = 0; j < 64; ++j) {
        float p0 = P[r0 * 64 + j];
        float p1 = P[(r0 + 1) * 64 + j];
        float w0 = W[j * 128 + c];
        float w1 = W[j * 128 + c + 64];
        a00 += p0 * w0; a01 += p0 * w1;
        a10 += p1 * w0; a11 += p1 * w1;
    }
    float sc = gSc[0];
    Wo[r0 * 128 + c]            = sc * a00;
    Wo[r0 * 128 + c + 64]       = sc * a01;
    Wo[(r0 + 1) * 128 + c]      = sc * a10;
    Wo[(r0 + 1) * 128 + c + 64] = sc * a11;
}

// ---------------------------------------------------------------------------
// per-node prep; also initializes the per-bucket global cursors.
// ---------------------------------------------------------------------------
__global__ void node_prep(const float* __restrict__ diags,
                          const float* m1, const float* m2, const float* m3,
                          const float* e1, const float* e2, const float* e3,
                          float* __restrict__ d_e2m, float* __restrict__ d_e3p,
                          float* __restrict__ gso2,
                          unsigned* __restrict__ gcur, int nbk, int n) {
    int i = blockIdx.x * blockDim.x + threadIdx.x;
    if (i < nbk) gcur[i] = (unsigned)i * REGION;
    if (i >= n) return;
    float d = diags[i];
    float p1 = safe_pow(d, e1[0]);
    float p2 = safe_pow(d, e2[0]);
    float p3 = safe_pow(d, e3[0]);
    float vm2 = m2[0];
    d_e2m[i] = vm2 * p2;
    d_e3p[i] = p3;
    gso2[i] = m1[0] * p1 + vm2 * p2 * p3 + m3[0];
}

// ---------------------------------------------------------------------------
// xw = x @ Wo^T — register-tiled GEMM; OUTPUT IN BF16.
// ---------------------------------------------------------------------------
#define XN 64
#define XS 132
__global__ __launch_bounds__(256) void xw_kernel(const float* __restrict__ x,
                                                 const float* __restrict__ Wo,
                                                 unsigned short* __restrict__ xwb,
                                                 int n) {
    __shared__ __align__(16) float xs[XN * XS];
    __shared__ __align__(16) float ws[DOUT * XS];
    int t = threadIdx.x;
    int base = blockIdx.x * XN;
    for (int f = t; f < DOUT * (DIN / 4); f += 256) {
        int r = f >> 5, c = f & 31;
        *(float4*)&ws[r * XS + c * 4] = *(const float4*)&Wo[r * DIN + c * 4];
    }
    for (int f = t; f < XN * (DIN / 4); f += 256) {
        int r = f >> 5, c = f & 31;
        int node = base + r;
        float4 v = make_float4(0.f, 0.f, 0.f, 0.f);
        if (node < n) v = *(const float4*)&x[(size_t)node * DIN + c * 4];
        *(float4*)&xs[r * XS + c * 4] = v;
    }
    __syncthreads();
    int tn = t >> 4;
    int td = t & 15;
    float acc[4][4] = {};
#pragma unroll 2
    for (int k4 = 0; k4 < DIN / 4; ++k4) {
        float4 a[4], w[4];
#pragma unroll
        for (int r = 0; r < 4; ++r) a[r] = *(const float4*)&xs[(tn * 4 + r) * XS + k4 * 4];
#pragma unroll
        for (int c = 0; c < 4; ++c) w[c] = *(const float4*)&ws[(td + c * 16) * XS + k4 * 4];
#pragma unroll
        for (int r = 0; r < 4; ++r)
#pragma unroll
            for (int c = 0; c < 4; ++c) acc[r][c] += dot4(a[r], w[c]);
    }
#pragma unroll
    for (int r = 0; r < 4; ++r) {
        int node = base + tn * 4 + r;
        if (node >= n) break;
#pragma unroll
        for (int c = 0; c < 4; ++c)
            xwb[(size_t)node * DOUT + td + c * 16] = f32_to_bf16(acc[r][c]);
    }
}

// ---------------------------------------------------------------------------
// FUSED binning: 1024 threads + int4 vectorization (round-21 win).
// Chunk geometry (NBLK=64, ~32-edge runs) preserves write locality.
// ---------------------------------------------------------------------------
__global__ __launch_bounds__(1024) void bin_scatter(const int* __restrict__ ei,
                                                    unsigned* __restrict__ gcur,
                                                    unsigned* __restrict__ bucketed,
                                                    int e_cnt, int chunk, int nbk) {
    __shared__ int h[NBK_STRIDE];
    int b = blockIdx.x, t = threadIdx.x;
    for (int j = t; j < NBK_STRIDE; j += 1024) h[j] = 0;
    __syncthreads();
    int lo = b * chunk, hi = min(lo + chunk, e_cnt);
    const int* cols = ei + e_cnt;
    int nfull = (hi - lo) >> 2;
    for (int g = t; g < nfull; g += 1024) {
        int4 c4 = *(const int4*)&cols[lo + 4 * g];
        atomicAdd(&h[c4.x >> BK_SHIFT], 1);
        atomicAdd(&h[c4.y >> BK_SHIFT], 1);
        atomicAdd(&h[c4.z >> BK_SHIFT], 1);
        atomicAdd(&h[c4.w >> BK_SHIFT], 1);
    }
    {
        int tb = lo + (nfull << 2);
        if (tb + t < hi) atomicAdd(&h[cols[tb + t] >> BK_SHIFT], 1);
    }
    __syncthreads();
    for (int j = t; j < nbk; j += 1024) {
        int c = h[j];
        h[j] = (c > 0) ? (int)atomicAdd(&gcur[j], (unsigned)c) : 0;
    }
    __syncthreads();
    for (int g = t; g < nfull; g += 1024) {
        int4 c4 = *(const int4*)&cols[lo + 4 * g];
        int4 s4 = *(const int4*)&ei[lo + 4 * g];
        int p0 = atomicAdd(&h[c4.x >> BK_SHIFT], 1);
        bucketed[p0] = ((unsigned)s4.x << BK_SHIFT) | (unsigned)(c4.x & (BK_COLS - 1));
        int p1 = atomicAdd(&h[c4.y >> BK_SHIFT], 1);
        bucketed[p1] = ((unsigned)s4.y << BK_SHIFT) | (unsigned)(c4.y & (BK_COLS - 1));
        int p2 = atomicAdd(&h[c4.z >> BK_SHIFT], 1);
        bucketed[p2] = ((unsigned)s4.z << BK_SHIFT) | (unsigned)(c4.z & (BK_COLS - 1));
        int p3 = atomicAdd(&h[c4.w >> BK_SHIFT], 1);
        bucketed[p3] = ((unsigned)s4.w << BK_SHIFT) | (unsigned)(c4.w & (BK_COLS - 1));
    }
    {
        int tb = lo + (nfull << 2);
        if (tb + t < hi) {
            int col = cols[tb + t];
            int src = ei[tb + t];
            int pos = atomicAdd(&h[col >> BK_SHIFT], 1);
            bucketed[pos] = ((unsigned)src << BK_SHIFT) | (unsigned)(col & (BK_COLS - 1));
        }
    }
}

// ---------------------------------------------------------------------------
// FUSED per-bucket CSR sort + gather + self-loop + bias + log-softmax.
// ROUND-21 LESSON: at 512 threads this sat at 50% occupancy, VALU 38%,
// BW 18% — exposed-latency-bound. 1024 threads (16 waves, 8 cols each)
// doubles resident waves; sort loops get 2x MLP. Same LDS/geometry.
// ---------------------------------------------------------------------------
__global__ __launch_bounds__(1024) void csr_gather(const unsigned* __restrict__ bucketed,
                                                   const unsigned* __restrict__ gcur,
                                                   const float* __restrict__ d_e2m,
                                                   const float* __restrict__ d_e3p,
                                                   const unsigned short* __restrict__ xwb,
                                                   const float* __restrict__ gso2,
                                                   const float* __restrict__ bias,
                                                   uint2* __restrict__ spill,
                                                   float* __restrict__ out, int n) {
    __shared__ __align__(16) uint2 sP[CCAP];
    __shared__ int shc[BK_COLS], scc[BK_COLS], posc[BK_COLS];
    __shared__ int offs[BK_COLS + 1];
    int b = blockIdx.x, t = threadIdx.x;
    int base = b * REGION;
    int cnt = (int)gcur[b] - base;
    bool fits = (cnt <= CCAP);

    if (t < BK_COLS) shc[t] = 0;
    __syncthreads();
    for (int i = t; i < cnt; i += 1024)
        atomicAdd(&shc[bucketed[base + i] & (BK_COLS - 1)], 1);
    __syncthreads();
    if (t < BK_COLS) scc[t] = shc[t];
    __syncthreads();
    for (int d = 1; d < BK_COLS; d <<= 1) {
        int u = 0;
        if (t < BK_COLS && t >= d) u = scc[t - d];
        __syncthreads();
        if (t < BK_COLS) scc[t] += u;
        __syncthreads();
    }
    if (t < BK_COLS) {
        int pre = scc[t] - shc[t];
        posc[t] = pre;
        offs[t] = pre;
    }
    if (t == 0) offs[BK_COLS] = cnt;
    __syncthreads();
    {
        uint2* dst = fits ? (uint2*)sP : (spill + base);
        for (int i = t; i < cnt; i += 1024) {
            unsigned k = bucketed[base + i];
            unsigned lc = k & (BK_COLS - 1);
            unsigned src = k >> BK_SHIFT;
            int q = atomicAdd(&posc[lc], 1);
            uint2 o;
            o.x = src;
            o.y = __float_as_uint(d_e2m[src]);
            dst[q] = o;
        }
    }
    __syncthreads();

    const uint2* P = fits ? (const uint2*)sP : (const uint2*)(spill + base);
    unsigned lane = t & 63;
    unsigned half = lane >> 5;
    unsigned hl = lane & 31;
    int wv = t >> 6;                      // 0..15, 8 cols each
    const unsigned* xw32 = (const unsigned*)xwb;
    int c0 = wv * 8;
    for (int c = c0; c < c0 + 8; ++c) {
        int node = b * BK_COLS + c;
        if (node >= n) break;             // wave-uniform (only last bucket)
        int lo = offs[c], hi = offs[c + 1];
        float accLo = 0.f, accHi = 0.f;
        int i = lo;
        for (; i + 8 <= hi; i += 8) {
            int e0 = i + 4 * (int)half;
            uint2 p0 = P[e0 + 0], p1 = P[e0 + 1], p2 = P[e0 + 2], p3 = P[e0 + 3];
            unsigned u0 = xw32[p0.x * 32u + hl];
            unsigned u1 = xw32[p1.x * 32u + hl];
            unsigned u2 = xw32[p2.x * 32u + hl];
            unsigned u3 = xw32[p3.x * 32u + hl];
            float w0 = __uint_as_float(p0.y), w1 = __uint_as_float(p1.y);
            float w2 = __uint_as_float(p2.y), w3 = __uint_as_float(p3.y);
            accLo += w0 * __uint_as_float(u0 << 16) + w1 * __uint_as_float(u1 << 16)
                   + w2 * __uint_as_float(u2 << 16) + w3 * __uint_as_float(u3 << 16);
            accHi += w0 * __uint_as_float(u0 & 0xFFFF0000u) + w1 * __uint_as_float(u1 & 0xFFFF0000u)
                   + w2 * __uint_as_float(u2 & 0xFFFF0000u) + w3 * __uint_as_float(u3 & 0xFFFF0000u);
        }
        for (; i + 4 <= hi; i += 4) {
            int e0 = i + 2 * (int)half;
            uint2 p0 = P[e0 + 0], p1 = P[e0 + 1];
            unsigned u0 = xw32[p0.x * 32u + hl];
            unsigned u1 = xw32[p1.x * 32u + hl];
            float w0 = __uint_as_float(p0.y), w1 = __uint_as_float(p1.y);
            accLo += w0 * __uint_as_float(u0 << 16) + w1 * __uint_as_float(u1 << 16);
            accHi += w0 * __uint_as_float(u0 & 0xFFFF0000u) + w1 * __uint_as_float(u1 & 0xFFFF0000u);
        }
        {
            int rem = hi - i;
            int j0 = 2 * (int)half;
            int j1 = min(j0 + 2, rem);
            for (int j = j0; j < j1; ++j) {
                uint2 p = P[i + j];
                unsigned u = xw32[p.x * 32u + hl];
                float w = __uint_as_float(p.y);
                accLo += w * __uint_as_float(u << 16);
                accHi += w * __uint_as_float(u & 0xFFFF0000u);
            }
        }
        accLo += __shfl_xor(accLo, 32);
        accHi += __shfl_xor(accHi, 32);

        unsigned us = xw32[(unsigned)node * 32u + hl];
        float xsLo = __uint_as_float(us << 16);
        float xsHi = __uint_as_float(us & 0xFFFF0000u);
        float2 bb = *(const float2*)&bias[2 * hl];
        float gs = gso2[node], dn = d_e3p[node];
        float vLo = gs * xsLo + 2.0f * bb.x + dn * accLo;
        float vHi = gs * xsHi + 2.0f * bb.y + dn * accHi;
        float m = fmaxf(vLo, vHi);
#pragma unroll
        for (int d = 1; d < 32; d <<= 1) m = fmaxf(m, __shfl_xor(m, d));
        float s = expf(vLo - m) + expf(vHi - m);
#pragma unroll
        for (int d = 1; d < 32; d <<= 1) s += __shfl_xor(s, d);
        if (half == 0) {
            float ls = logf(s);
            float2 o;
            o.x = vLo - m - ls;
            o.y = vHi - m - ls;
            *(float2*)&out[(size_t)node * DOUT + 2 * hl] = o;
        }
    }
}

// ---------------------------------------------------------------------------
extern "C" void kernel_launch(void* const* d_in, const int* in_sizes, int n_in,
                              void* d_out, int out_size, void* d_ws, size_t ws_size,
                              hipStream_t stream) {
    const float* x     = (const float*)d_in[0];
    const int*   ei    = (const int*)d_in[1];
    const float* diags = (const float*)d_in[3];
    const float* W     = (const float*)d_in[4];
    const float* b     = (const float*)d_in[5];
    const float* m1    = (const float*)d_in[6];
    const float* m2    = (const float*)d_in[7];
    const float* m3    = (const float*)d_in[8];
    const float* e1    = (const float*)d_in[9];
    const float* e2    = (const float*)d_in[10];
    const float* e3    = (const float*)d_in[11];
    float* out = (float*)d_out;

    const int n = in_sizes[3];            // 100000
    const int e_cnt = in_sizes[1] / 2;    // 1600000
    const int nbk = (n + BK_COLS - 1) >> BK_SHIFT;          // 782 buckets
    const int chunk = (e_cnt + NBLK - 1) / NBLK;            // 25000 edges/chunk

    char* ws = (char*)d_ws;
    // --- small-matrix region (fixed offsets) ---
    float*    Wo   = (float*)ws;                 // 8192 floats = 32KB
    float*    gG   = (float*)(ws + 32768);       // 12 x 4096 floats
    float*    gT   = gG  + 4096;
    float*    gA   = gT  + 4096;
    float*    gAn  = gA  + 4096;
    float*    gA0  = gAn + 4096;
    float*    gP   = gA0 + 4096;
    float*    gPn  = gP  + 4096;
    float*    gB0  = gPn + 4096;
    float*    gB1  = gB0 + 4096;
    float*    gB2  = gB1 + 4096;
    float*    gB3  = gB2 + 4096;
    float*    gB4  = gB3 + 4096;
    float*    gSc  = gB4 + 4096;                 // 2 floats (pad to 64)
    // --- big arrays ---
    float*          d_e2m    = gSc + 64;               // n
    float*          d_e3p    = d_e2m + n;              // n
    float*          gso2     = d_e3p + n;              // n
    unsigned short* xwb      = (unsigned short*)(gso2 + n);       // n*64 bf16
    unsigned*       gcur     = (unsigned*)(xwb + (size_t)n * DOUT); // nbk+8
    uintptr_t bb_ = ((uintptr_t)(gcur + nbk + 8) + 15) & ~(uintptr_t)15;
    unsigned*       bucketed = (unsigned*)bb_;                     // nbk*REGION u32
    uint2*          spill    = (uint2*)(bucketed + (size_t)nbk * REGION); // nbk*REGION u2

    // ---- Bjorck chain: 14 small multi-block dispatches ----------------------
    gram_pass<<<8, 256, 0, stream>>>(W, gG);                              // G
    mm_pass<<<8, 256, 0, stream>>>(gG, nullptr, gG, gT, nullptr, nullptr); // H = G^2
    mm_pass<<<8, 256, 0, stream>>>(gT, nullptr, gT, gA, nullptr, nullptr); // H2 = G^4
    power_prep<<<1, 256, 0, stream>>>(gA, gG, gSc, gA0, gB0);             // sc,rs,A0,B0
    mm_pass<<<8, 256, 0, stream>>>(gA0, nullptr, gB0, gT, nullptr, nullptr); // T = A0@B0
    mm_pass<<<8, 256, 0, stream>>>(gT, nullptr, gB0, gA, nullptr, gB1);   // A1 (+B1)
    mm_pass<<<16, 256, 0, stream>>>(gB0, gA, gB1, gP, gT, nullptr);       // P=B0B1, T=A1B1
    mm_pass<<<8, 256, 0, stream>>>(gT, nullptr, gB1, gAn, nullptr, gB2);  // A2 (+B2)
    mm_pass<<<16, 256, 0, stream>>>(gP, gAn, gB2, gPn, gT, nullptr);      // P=PB2, T=A2B2
    mm_pass<<<8, 256, 0, stream>>>(gT, nullptr, gB2, gA, nullptr, gB3);   // A3 (+B3)
    mm_pass<<<16, 256, 0, stream>>>(gPn, gA, gB3, gP, gT, nullptr);       // P=PB3, T=A3B3
    mm_pass<<<8, 256, 0, stream>>>(gT, nullptr, gB3, gAn, nullptr, gB4);  // A4 (+B4)
    mm_pass<<<8, 256, 0, stream>>>(gP, nullptr, gB4, gPn, nullptr, nullptr); // P final
    wo_pass<<<8, 256, 0, stream>>>(W, gPn, gSc, Wo);                      // Wo

    // ---- node prep (+ gcur init) + feature transform -----------------------
    node_prep<<<(n + 255) / 256, 256, 0, stream>>>(diags, m1, m2, m3, e1, e2, e3,
                                                   d_e2m, d_e3p, gso2, gcur, nbk, n);
    xw_kernel<<<(n + XN - 1) / XN, 256, 0, stream>>>(x, Wo, xwb, n);
    // ---- fused binning (1024 threads, int4 MLP) -----------------------------
    bin_scatter<<<NBLK, 1024, 0, stream>>>(ei, gcur, bucketed, e_cnt, chunk, nbk);
    // ---- fused per-bucket CSR sort + gather + softmax (1024 threads) --------
    csr_gather<<<nbk, 1024, 0, stream>>>(bucketed, gcur, d_e2m, d_e3p,
                                         xwb, gso2, b, spill, out, n);
}